// Round 1
// baseline (182.462 us; speedup 1.0000x reference)
//
#include <hip/hip_runtime.h>
#include <math.h>

// ---------------------------------------------------------------------------
// Kernel 1: per-(b,c) reduction of feat. One block per 256x256 plane.
// Produces sumF[b*64+c] = spatial sum of the (possibly depthwise-conv'd)
// channel, computed analytically via border-rectangle sums.
// ---------------------------------------------------------------------------
__global__ __launch_bounds__(256) void k_feat_reduce(
    const float* __restrict__ feat,
    const float* __restrict__ w_hw, const float* __restrict__ b_hw,
    const float* __restrict__ w_w,  const float* __restrict__ b_w,
    const float* __restrict__ w_h,  const float* __restrict__ b_h,
    float* __restrict__ sumF)
{
  const int plane = blockIdx.x;        // b*64 + c
  const int c = plane & 63;
  const int tid = threadIdx.x;         // 256 threads
  const float4* x4 = reinterpret_cast<const float4*>(feat) + (size_t)plane * 16384;

  __shared__ float s_rs[10];    // row sums: rows 0..4 -> 0..4, rows 251..255 -> 5..9
  __shared__ float s_cs[10];    // col sums: cols 0..4 -> 0..4, cols 251..255 -> 5..9
  __shared__ float s_corner[4]; // (0,0),(0,255),(255,0),(255,255)
  __shared__ float s_part[4];
  if (tid < 10) { s_rs[tid] = 0.f; s_cs[tid] = 0.f; }
  if (tid < 4)  { s_corner[tid] = 0.f; }
  __syncthreads();

  float tot = 0.f;
  if (c < 40) {
    // identity channels: just the total sum
    #pragma unroll 4
    for (int it = 0; it < 64; ++it) {
      float4 v = x4[it * 256 + tid];
      tot += (v.x + v.y) + (v.z + v.w);
    }
  } else {
    for (int it = 0; it < 64; ++it) {
      const int f4i = it * 256 + tid;
      float4 v = x4[f4i];
      float s4 = (v.x + v.y) + (v.z + v.w);
      tot += s4;
      const int row = f4i >> 6;          // 0..255
      const int cb  = (f4i & 63) << 2;   // starting column of this float4
      if (row < 5)        atomicAdd(&s_rs[row], s4);
      else if (row > 250) atomicAdd(&s_rs[row - 246], s4);
      if (cb == 0) {
        atomicAdd(&s_cs[0], v.x); atomicAdd(&s_cs[1], v.y);
        atomicAdd(&s_cs[2], v.z); atomicAdd(&s_cs[3], v.w);
        if (row == 0)   s_corner[0] = v.x;
        if (row == 255) s_corner[2] = v.x;
      } else if (cb == 4) {
        atomicAdd(&s_cs[4], v.x);
      } else if (cb == 248) {
        atomicAdd(&s_cs[5], v.w);               // col 251
      } else if (cb == 252) {
        atomicAdd(&s_cs[6], v.x); atomicAdd(&s_cs[7], v.y);
        atomicAdd(&s_cs[8], v.z); atomicAdd(&s_cs[9], v.w);
        if (row == 0)   s_corner[1] = v.w;
        if (row == 255) s_corner[3] = v.w;
      }
    }
  }

  // block reduce total
  for (int off = 32; off; off >>= 1) tot += __shfl_down(tot, off, 64);
  if ((tid & 63) == 0) s_part[tid >> 6] = tot;
  __syncthreads();

  if (tid == 0) {
    const float T = (s_part[0] + s_part[1]) + (s_part[2] + s_part[3]);
    float S;
    if (c < 40) {
      S = T;
    } else {
      float topP[6], botP[6], leftP[6], rightP[6];
      topP[0] = botP[0] = leftP[0] = rightP[0] = 0.f;
      for (int k = 0; k < 5; ++k) {
        topP[k+1]   = topP[k]   + s_rs[k];      // exclude rows 0..k
        botP[k+1]   = botP[k]   + s_rs[9-k];    // exclude rows 255..255-k
        leftP[k+1]  = leftP[k]  + s_cs[k];
        rightP[k+1] = rightP[k] + s_cs[9-k];
      }
      auto rect = [&](int du, int dv) -> float {
        // sum of x over rows [max(0,du),255+min(0,du)] x cols [max(0,dv),255+min(0,dv)]
        float r = T;
        if (du > 0) r -= topP[du]; else if (du < 0) r -= botP[-du];
        if (dv > 0) r -= leftP[dv]; else if (dv < 0) r -= rightP[-dv];
        // corner add-back only occurs for |du|==|dv|==1 (the 3x3 kernel)
        if (du > 0 && dv > 0) r += s_corner[0];
        else if (du > 0 && dv < 0) r += s_corner[1];
        else if (du < 0 && dv > 0) r += s_corner[2];
        else if (du < 0 && dv < 0) r += s_corner[3];
        return r;
      };
      if (c < 48) {                       // 3x3 depthwise, pad (1,1)
        const int g = c - 40; const float* w = w_hw + g * 9;
        S = 65536.f * b_hw[g];
        for (int u = 0; u < 3; ++u)
          for (int v = 0; v < 3; ++v)
            S += w[u*3+v] * rect(u-1, v-1);
      } else if (c < 56) {                // 1x11 depthwise, pad (0,5)
        const int g = c - 48; const float* w = w_w + g * 11;
        S = 65536.f * b_w[g];
        for (int v = 0; v < 11; ++v) S += w[v] * rect(0, v-5);
      } else {                            // 11x1 depthwise, pad (5,0)
        const int g = c - 56; const float* w = w_h + g * 11;
        S = 65536.f * b_h[g];
        for (int u = 0; u < 11; ++u) S += w[u] * rect(u-5, 0);
      }
    }
    sumF[plane] = S;
  }
}

// ---------------------------------------------------------------------------
// Kernel 2: per-batch scalar sumP[b] = sum over the final "pred" plane:
//   up = bilinear2x(pred)  (half-pixel, edge clamp)
//   p = sigmoid(up); pa = p*(1-sigmoid(p)) + p
//   final = p + conv3x3(pa) + dw_b  -> sum = sum(p) + 65536*dw_b + sum w*rect(pa)
// One block per batch, thread = output column, loop over output rows.
// ---------------------------------------------------------------------------
__global__ __launch_bounds__(256) void k_pred_reduce(
    const float* __restrict__ pred,
    const float* __restrict__ dw_w, const float* __restrict__ dw_b,
    float* __restrict__ sumP)
{
  const int b = blockIdx.x;
  const int j = threadIdx.x;            // output column 0..255
  __shared__ __align__(16) float s_in[16384];   // 128x128 input plane (64 KB)

  const float4* src = reinterpret_cast<const float4*>(pred) + (size_t)b * 4096;
  float4* dst = reinterpret_cast<float4*>(s_in);
  for (int i = j; i < 4096; i += 256) dst[i] = src[i];
  __syncthreads();

  // column interpolation for this thread (jax bilinear 2x: even .25/.75, odd .75/.25, clamped)
  const int kj = j >> 1;
  int c0, c1; float wc0, wc1;
  if ((j & 1) == 0) { c0 = (kj > 0) ? kj - 1 : 0; c1 = kj; wc0 = 0.25f; wc1 = 0.75f; }
  else              { c0 = kj; c1 = (kj < 127) ? kj + 1 : 127; wc0 = 0.75f; wc1 = 0.25f; }

  float accP = 0.f, accT = 0.f, accC = 0.f;
  float r0v = 0.f, r255v = 0.f, corner_top = 0.f, corner_bot = 0.f;

  for (int i = 0; i < 256; ++i) {
    const int ki = i >> 1;
    int r0, r1; float wr0, wr1;
    if ((i & 1) == 0) { r0 = (ki > 0) ? ki - 1 : 0; r1 = ki; wr0 = 0.25f; wr1 = 0.75f; }
    else              { r0 = ki; r1 = (ki < 127) ? ki + 1 : 127; wr0 = 0.75f; wr1 = 0.25f; }
    const float v = wr0 * (wc0 * s_in[r0*128 + c0] + wc1 * s_in[r0*128 + c1])
                  + wr1 * (wc0 * s_in[r1*128 + c0] + wc1 * s_in[r1*128 + c1]);
    const float p  = 1.f / (1.f + expf(-v));
    const float pm = 1.f - 1.f / (1.f + expf(-p));
    const float pa = p * pm + p;
    accP += p; accT += pa;
    if (i == 0)   r0v   = pa;
    if (i == 255) r255v = pa;
    if (j == 0 || j == 255) {
      accC += pa;
      if (i == 0)   corner_top = pa;
      if (i == 255) corner_bot = pa;
    }
  }
  __syncthreads();   // done reading s_in; reuse it as reduction scratch
  // scratch layout in s_in: [0..3]=P, [4..7]=T, [8..11]=R0, [12..15]=R255,
  //                         [20]=C0,[21]=C255, [24..27]=corners
  if (j == 0)   { s_in[20] = accC; s_in[24] = corner_top; s_in[26] = corner_bot; }
  if (j == 255) { s_in[21] = accC; s_in[25] = corner_top; s_in[27] = corner_bot; }
  float a0 = accP, a1 = accT, a2 = r0v, a3 = r255v;
  for (int off = 32; off; off >>= 1) {
    a0 += __shfl_down(a0, off, 64); a1 += __shfl_down(a1, off, 64);
    a2 += __shfl_down(a2, off, 64); a3 += __shfl_down(a3, off, 64);
  }
  const int wv = j >> 6;
  if ((j & 63) == 0) { s_in[0+wv] = a0; s_in[4+wv] = a1; s_in[8+wv] = a2; s_in[12+wv] = a3; }
  __syncthreads();

  if (j == 0) {
    const float P    = (s_in[0] + s_in[1]) + (s_in[2] + s_in[3]);
    const float T    = (s_in[4] + s_in[5]) + (s_in[6] + s_in[7]);
    const float R0   = (s_in[8] + s_in[9]) + (s_in[10] + s_in[11]);
    const float R255 = (s_in[12] + s_in[13]) + (s_in[14] + s_in[15]);
    const float C0 = s_in[20], C255 = s_in[21];
    const float k00 = s_in[24], k01 = s_in[25], k10 = s_in[26], k11 = s_in[27];
    auto rect = [&](int du, int dv) -> float {
      float r = T;
      if (du > 0) r -= R0; else if (du < 0) r -= R255;
      if (dv > 0) r -= C0; else if (dv < 0) r -= C255;
      if (du > 0 && dv > 0) r += k00;
      else if (du > 0 && dv < 0) r += k01;
      else if (du < 0 && dv > 0) r += k10;
      else if (du < 0 && dv < 0) r += k11;
      return r;
    };
    float S = P + 65536.f * dw_b[0];
    for (int u = 0; u < 3; ++u)
      for (int v = 0; v < 3; ++v)
        S += dw_w[u*3+v] * rect(u-1, v-1);
    sumP[b] = S;
  }
}

// ---------------------------------------------------------------------------
// Kernel 3: tiny MLP/LN/gate tail. One block per batch, 128 threads (2 waves).
// ---------------------------------------------------------------------------
__device__ __forceinline__ float wsum64(float v) {
  for (int off = 32; off; off >>= 1) v += __shfl_xor(v, off, 64);
  return v;
}

__global__ __launch_bounds__(128) void k_tail(
    const float* __restrict__ sumF, const float* __restrict__ sumP,
    const float* __restrict__ head,
    const float* __restrict__ pt_w, const float* __restrict__ pt_b,
    const float* __restrict__ ht_w, const float* __restrict__ ht_b,
    const float* __restrict__ pg_w, const float* __restrict__ pg_b,
    const float* __restrict__ hg_w, const float* __restrict__ hg_b,
    const float* __restrict__ fc_w, const float* __restrict__ fc_b,
    const float* __restrict__ pni_g, const float* __restrict__ pni_b,
    const float* __restrict__ hni_g, const float* __restrict__ hni_b,
    const float* __restrict__ pno_g, const float* __restrict__ pno_b,
    const float* __restrict__ hno_g, const float* __restrict__ hno_b,
    const float* __restrict__ fcn_g, const float* __restrict__ fcn_b,
    float* __restrict__ out)
{
  const int b = blockIdx.x;
  const int t = threadIdx.x;      // 0..127
  const int ln = t & 63;
  __shared__ float a[64], hd[64], pf[128], hf[128], gate[64];
  __shared__ float hgate[64], pgate[64], pfo[64], hfo[64], upd[64];

  if (t < 64) { a[t] = sumF[b*64 + t] * sumP[b]; hd[t] = head[b*64 + t]; }
  __syncthreads();

  { // pred_feat / head_feat linears (128 outputs each)
    float sp = pt_b[t], sh = ht_b[t];
    for (int k = 0; k < 64; ++k) {
      sp += a[k]  * pt_w[t*64 + k];
      sh += hd[k] * ht_w[t*64 + k];
    }
    pf[t] = sp; hf[t] = sh;
  }
  __syncthreads();
  if (t < 64) gate[t] = hf[t] * pf[t];
  __syncthreads();

  // gate linears: wave 0 -> head_gate (hg_w), wave 1 -> pred_gate (pg_w)
  float glin;
  if (t < 64) {
    float s = hg_b[ln];
    for (int k = 0; k < 64; ++k) s += gate[k] * hg_w[ln*64 + k];
    glin = s;
  } else {
    float s = pg_b[ln];
    for (int k = 0; k < 64; ++k) s += gate[k] * pg_w[ln*64 + k];
    glin = s;
  }
  { // LN + sigmoid per wave
    const float m = wsum64(glin) * (1.f/64.f);
    const float d = glin - m;
    const float var = wsum64(d*d) * (1.f/64.f);
    const float* g  = (t < 64) ? hni_g : pni_g;
    const float* bb = (t < 64) ? hni_b : pni_b;
    const float y = d / sqrtf(var + 1e-5f) * g[ln] + bb[ln];
    const float sg = 1.f / (1.f + expf(-y));
    if (t < 64) hgate[ln] = sg; else pgate[ln] = sg;
  }
  { // LN of the out-halves: wave 0 -> head_feat_out, wave 1 -> pred_feat_out
    const float x = (t < 64) ? hf[64 + ln] : pf[64 + ln];
    const float m = wsum64(x) * (1.f/64.f);
    const float d = x - m;
    const float var = wsum64(d*d) * (1.f/64.f);
    const float* g  = (t < 64) ? hno_g : pno_g;
    const float* bb = (t < 64) ? hno_b : pno_b;
    const float y = d / sqrtf(var + 1e-5f) * g[ln] + bb[ln];
    if (t < 64) hfo[ln] = y; else pfo[ln] = y;
  }
  __syncthreads();
  if (t < 64) upd[t] = pgate[t] * pfo[t] + hgate[t] * hfo[t];
  __syncthreads();
  if (t < 64) {
    float s = fc_b[t];
    for (int k = 0; k < 64; ++k) s += upd[k] * fc_w[t*64 + k];
    const float m = wsum64(s) * (1.f/64.f);
    const float d = s - m;
    const float var = wsum64(d*d) * (1.f/64.f);
    const float y = d / sqrtf(var + 1e-5f) * fcn_g[t] + fcn_b[t];
    out[b*64 + t] = fmaxf(y, 0.f);
  }
}

// ---------------------------------------------------------------------------
extern "C" void kernel_launch(void* const* d_in, const int* in_sizes, int n_in,
                              void* d_out, int out_size, void* d_ws, size_t ws_size,
                              hipStream_t stream) {
  (void)in_sizes; (void)n_in; (void)out_size; (void)ws_size;
  const float* feat     = (const float*)d_in[0];
  const float* head     = (const float*)d_in[1];
  const float* pred     = (const float*)d_in[2];
  const float* dw_w     = (const float*)d_in[3];
  const float* dw_b     = (const float*)d_in[4];
  const float* inc_hw_w = (const float*)d_in[5];
  const float* inc_hw_b = (const float*)d_in[6];
  const float* inc_w_w  = (const float*)d_in[7];
  const float* inc_w_b  = (const float*)d_in[8];
  const float* inc_h_w  = (const float*)d_in[9];
  const float* inc_h_b  = (const float*)d_in[10];
  const float* pt_w  = (const float*)d_in[11];
  const float* pt_b  = (const float*)d_in[12];
  const float* ht_w  = (const float*)d_in[13];
  const float* ht_b  = (const float*)d_in[14];
  const float* pg_w  = (const float*)d_in[15];
  const float* pg_b  = (const float*)d_in[16];
  const float* hg_w  = (const float*)d_in[17];
  const float* hg_b  = (const float*)d_in[18];
  const float* fc_w  = (const float*)d_in[19];
  const float* fc_b  = (const float*)d_in[20];
  const float* pni_g = (const float*)d_in[21];
  const float* pni_b = (const float*)d_in[22];
  const float* hni_g = (const float*)d_in[23];
  const float* hni_b = (const float*)d_in[24];
  const float* pno_g = (const float*)d_in[25];
  const float* pno_b = (const float*)d_in[26];
  const float* hno_g = (const float*)d_in[27];
  const float* hno_b = (const float*)d_in[28];
  const float* fcn_g = (const float*)d_in[29];
  const float* fcn_b = (const float*)d_in[30];

  float* out  = (float*)d_out;
  float* sumF = (float*)d_ws;        // 1024 floats
  float* sumP = sumF + 1024;         // 16 floats

  k_feat_reduce<<<1024, 256, 0, stream>>>(feat, inc_hw_w, inc_hw_b,
                                          inc_w_w, inc_w_b, inc_h_w, inc_h_b, sumF);
  k_pred_reduce<<<16, 256, 0, stream>>>(pred, dw_w, dw_b, sumP);
  k_tail<<<16, 128, 0, stream>>>(sumF, sumP, head,
                                 pt_w, pt_b, ht_w, ht_b,
                                 pg_w, pg_b, hg_w, hg_b, fc_w, fc_b,
                                 pni_g, pni_b, hni_g, hni_b,
                                 pno_g, pno_b, hno_g, hno_b,
                                 fcn_g, fcn_b, out);
}

// Round 2
// 64.984 us; speedup vs baseline: 2.8078x; 2.8078x over previous
//
#include <hip/hip_runtime.h>
#include <math.h>

// ws layout: sumF[1024] floats, then predpart[16*8*8] floats.
//
// Identities used (verified exact in round 0):
//  - sum(irfft2(rfft2(p)*rfft2(f))) over space = sum(p)*sum(f)   (circular conv)
//  - spatial sum of zero-padded depthwise conv = sum_w w[u,v]*RectSum + N*b,
//    where RectSum needs only the plane total and <=5-wide border strips.

// ---------------------------------------------------------------------------
// Kernel A (fused): blocks 0..127 = pred partial reduction (16 batches x 8 row
// groups); blocks 128..1151 = pure branch-free plane sums of feat.
// ---------------------------------------------------------------------------
__global__ __launch_bounds__(256) void k_fused(
    const float* __restrict__ feat,
    const float* __restrict__ pred,
    float* __restrict__ sumF,        // [1024] plane totals
    float* __restrict__ predpart)    // [16][8][8]
{
  const int tid  = threadIdx.x;
  const int lane = tid & 63;
  const int wid  = tid >> 6;
  __shared__ float red[12];

  if (blockIdx.x >= 128) {
    // ---- pure plane sum: zero branches, unroll 8, 4 independent acc chains
    const int plane = blockIdx.x - 128;
    const float4* x4 = reinterpret_cast<const float4*>(feat) + (size_t)plane * 16384;
    float ax = 0.f, ay = 0.f, az = 0.f, aw = 0.f;
    #pragma unroll 8
    for (int it = 0; it < 64; ++it) {
      const float4 v = x4[it * 256 + tid];
      ax += v.x; ay += v.y; az += v.z; aw += v.w;
    }
    float tot = (ax + ay) + (az + aw);
    #pragma unroll
    for (int off = 32; off; off >>= 1) tot += __shfl_down(tot, off, 64);
    if (lane == 0) red[wid] = tot;
    __syncthreads();
    if (tid == 0) sumF[plane] = (red[0] + red[1]) + (red[2] + red[3]);
    return;
  }

  // ---- pred partial: block pb handles output rows [g*32, g*32+32)
  const int pb = blockIdx.x;
  const int b  = pb >> 3;
  const int g  = pb & 7;
  const int j  = tid;                 // output column 0..255
  const float* src = pred + (size_t)b * 16384;

  // jax bilinear 2x (half-pixel, edge clamp): even .25/.75, odd .75/.25
  const int kj = j >> 1;
  int c0, c1; float wc0, wc1;
  if ((j & 1) == 0) { c0 = (kj > 0) ? kj - 1 : 0; c1 = kj; wc0 = 0.25f; wc1 = 0.75f; }
  else              { c0 = kj; c1 = (kj < 127) ? kj + 1 : 127; wc0 = 0.75f; wc1 = 0.25f; }

  float accP = 0.f, accT = 0.f, accC = 0.f, redge = 0.f, cornA = 0.f, cornB = 0.f;
  const int i0 = g * 32;
  #pragma unroll 4
  for (int i = i0; i < i0 + 32; ++i) {
    const int ki = i >> 1;
    int r0, r1; float wr0, wr1;
    if ((i & 1) == 0) { r0 = (ki > 0) ? ki - 1 : 0; r1 = ki; wr0 = 0.25f; wr1 = 0.75f; }
    else              { r0 = ki; r1 = (ki < 127) ? ki + 1 : 127; wr0 = 0.75f; wr1 = 0.25f; }
    const float v = wr0 * (wc0 * src[r0*128 + c0] + wc1 * src[r0*128 + c1])
                  + wr1 * (wc0 * src[r1*128 + c0] + wc1 * src[r1*128 + c1]);
    const float p  = 1.f / (1.f + expf(-v));
    const float pm = 1.f - 1.f / (1.f + expf(-p));
    const float pa = p * pm + p;
    accP += p; accT += pa;
    if (j == 0 || j == 255) accC += pa;
    if (i == 0 || i == 255) {         // only reachable in g==0 / g==7
      redge += pa;
      if (j == 0)   cornA = pa;
      if (j == 255) cornB = pa;
    }
  }
  // deterministic block reduce of {accP, accT, redge}
  float a0 = accP, a1 = accT, a2 = redge;
  #pragma unroll
  for (int off = 32; off; off >>= 1) {
    a0 += __shfl_down(a0, off, 64);
    a1 += __shfl_down(a1, off, 64);
    a2 += __shfl_down(a2, off, 64);
  }
  if (lane == 0) { red[wid] = a0; red[4 + wid] = a1; red[8 + wid] = a2; }
  __syncthreads();
  float* pp = predpart + pb * 8;
  if (tid == 0) {
    pp[0] = (red[0] + red[1]) + (red[2] + red[3]);
    pp[1] = (red[4] + red[5]) + (red[6] + red[7]);
    pp[4] = (red[8] + red[9]) + (red[10] + red[11]);
    pp[2] = accC; pp[5] = cornA;
  }
  if (tid == 255) { pp[3] = accC; pp[6] = cornB; }
}

// ---------------------------------------------------------------------------
// Kernel B: border corrections for the 384 conv planes (reads ~8 MB, L3-hot).
// Overwrites sumF[plane] with the conv'd-channel spatial sum.
// ---------------------------------------------------------------------------
__global__ __launch_bounds__(256) void k_border(
    const float* __restrict__ feat,
    const float* __restrict__ w_hw, const float* __restrict__ b_hw,
    const float* __restrict__ w_w,  const float* __restrict__ b_w,
    const float* __restrict__ w_h,  const float* __restrict__ b_h,
    float* __restrict__ sumF)
{
  const int cp = blockIdx.x;           // 0..383
  const int b  = cp / 24;
  const int ci = cp % 24;
  const int c  = 40 + ci;
  const float* x = feat + (size_t)(b * 64 + c) * 65536;
  const int t = threadIdx.x, lane = t & 63, wid = t >> 6;

  float rv[10], cv[10];
  #pragma unroll
  for (int r = 0; r < 10; ++r) { const int rr = (r < 5) ? r : r + 246; rv[r] = x[rr * 256 + t]; }
  #pragma unroll
  for (int k = 0; k < 10; ++k) { const int cc = (k < 5) ? k : k + 246; cv[k] = x[t * 256 + cc]; }

  __shared__ float red[20][4];
  #pragma unroll
  for (int v = 0; v < 10; ++v) {
    float s = rv[v], s2 = cv[v];
    #pragma unroll
    for (int off = 32; off; off >>= 1) { s += __shfl_down(s, off, 64); s2 += __shfl_down(s2, off, 64); }
    if (lane == 0) { red[v][wid] = s; red[10 + v][wid] = s2; }
  }
  __syncthreads();

  if (t == 0) {
    float rs[10], cs[10];
    #pragma unroll
    for (int v = 0; v < 10; ++v) {
      rs[v] = (red[v][0] + red[v][1]) + (red[v][2] + red[v][3]);
      cs[v] = (red[10+v][0] + red[10+v][1]) + (red[10+v][2] + red[10+v][3]);
    }
    const float k00 = x[0], k01 = x[255], k10 = x[255 * 256], k11 = x[255 * 256 + 255];
    const float T = sumF[b * 64 + c];

    float topP[6], botP[6], leftP[6], rightP[6];
    topP[0] = botP[0] = leftP[0] = rightP[0] = 0.f;
    #pragma unroll
    for (int k = 0; k < 5; ++k) {
      topP[k+1]   = topP[k]   + rs[k];
      botP[k+1]   = botP[k]   + rs[9-k];
      leftP[k+1]  = leftP[k]  + cs[k];
      rightP[k+1] = rightP[k] + cs[9-k];
    }
    auto rect = [&](int du, int dv) -> float {
      float r = T;
      if (du > 0) r -= topP[du]; else if (du < 0) r -= botP[-du];
      if (dv > 0) r -= leftP[dv]; else if (dv < 0) r -= rightP[-dv];
      if (du > 0 && dv > 0) r += k00;
      else if (du > 0 && dv < 0) r += k01;
      else if (du < 0 && dv > 0) r += k10;
      else if (du < 0 && dv < 0) r += k11;
      return r;
    };
    float S;
    if (c < 48) {                       // 3x3 depthwise, pad (1,1)
      const int gg = c - 40; const float* w = w_hw + gg * 9;
      S = 65536.f * b_hw[gg];
      #pragma unroll
      for (int u = 0; u < 3; ++u)
        #pragma unroll
        for (int v = 0; v < 3; ++v)
          S += w[u*3+v] * rect(u-1, v-1);
    } else if (c < 56) {                // 1x11 depthwise, pad (0,5)
      const int gg = c - 48; const float* w = w_w + gg * 11;
      S = 65536.f * b_w[gg];
      #pragma unroll
      for (int v = 0; v < 11; ++v) S += w[v] * rect(0, v-5);
    } else {                            // 11x1 depthwise, pad (5,0)
      const int gg = c - 56; const float* w = w_h + gg * 11;
      S = 65536.f * b_h[gg];
      #pragma unroll
      for (int u = 0; u < 11; ++u) S += w[u] * rect(u-5, 0);
    }
    sumF[b * 64 + c] = S;
  }
}

// ---------------------------------------------------------------------------
// Kernel C: combine pred partials -> sumP, then the MLP/LN/gate tail.
// One block per batch, 128 threads (2 waves).
// ---------------------------------------------------------------------------
__device__ __forceinline__ float wsum64(float v) {
  #pragma unroll
  for (int off = 32; off; off >>= 1) v += __shfl_xor(v, off, 64);
  return v;
}

__global__ __launch_bounds__(128) void k_tail(
    const float* __restrict__ sumF, const float* __restrict__ predpart,
    const float* __restrict__ head,
    const float* __restrict__ dw_w, const float* __restrict__ dw_b,
    const float* __restrict__ pt_w, const float* __restrict__ pt_b,
    const float* __restrict__ ht_w, const float* __restrict__ ht_b,
    const float* __restrict__ pg_w, const float* __restrict__ pg_b,
    const float* __restrict__ hg_w, const float* __restrict__ hg_b,
    const float* __restrict__ fc_w, const float* __restrict__ fc_b,
    const float* __restrict__ pni_g, const float* __restrict__ pni_b,
    const float* __restrict__ hni_g, const float* __restrict__ hni_b,
    const float* __restrict__ pno_g, const float* __restrict__ pno_b,
    const float* __restrict__ hno_g, const float* __restrict__ hno_b,
    const float* __restrict__ fcn_g, const float* __restrict__ fcn_b,
    float* __restrict__ out)
{
  const int b = blockIdx.x;
  const int t = threadIdx.x;      // 0..127
  const int ln = t & 63;
  __shared__ float a[64], hd[64], pf[128], hf[128], gate[64];
  __shared__ float hgate[64], pgate[64], pfo[64], hfo[64], upd[64];
  __shared__ float s_sP;

  const float sf = (t < 64) ? sumF[b * 64 + t] : 0.f;
  if (t < 64) hd[t] = head[b * 64 + t];

  if (t == 0) {
    // combine the 8 row-group partials (fixed order -> deterministic)
    const float* pp = predpart + b * 64;   // [8][8]
    float P = 0.f, T = 0.f, C0 = 0.f, C255 = 0.f;
    #pragma unroll
    for (int g = 0; g < 8; ++g) {
      P += pp[g*8 + 0]; T += pp[g*8 + 1]; C0 += pp[g*8 + 2]; C255 += pp[g*8 + 3];
    }
    const float R0 = pp[0*8 + 4], R255 = pp[7*8 + 4];
    const float k00 = pp[0*8 + 5], k01 = pp[0*8 + 6];
    const float k10 = pp[7*8 + 5], k11 = pp[7*8 + 6];
    auto rect = [&](int du, int dv) -> float {
      float r = T;
      if (du > 0) r -= R0; else if (du < 0) r -= R255;
      if (dv > 0) r -= C0; else if (dv < 0) r -= C255;
      if (du > 0 && dv > 0) r += k00;
      else if (du > 0 && dv < 0) r += k01;
      else if (du < 0 && dv > 0) r += k10;
      else if (du < 0 && dv < 0) r += k11;
      return r;
    };
    float S = P + 65536.f * dw_b[0];
    #pragma unroll
    for (int u = 0; u < 3; ++u)
      #pragma unroll
      for (int v = 0; v < 3; ++v)
        S += dw_w[u*3+v] * rect(u-1, v-1);
    s_sP = S;
  }
  __syncthreads();
  if (t < 64) a[t] = sf * s_sP;
  __syncthreads();

  { // pred_feat / head_feat linears (128 outputs each), float4 weight rows
    const float4* ptw4 = reinterpret_cast<const float4*>(pt_w) + t * 16;
    const float4* htw4 = reinterpret_cast<const float4*>(ht_w) + t * 16;
    const float4* a4  = reinterpret_cast<const float4*>(a);
    const float4* hd4 = reinterpret_cast<const float4*>(hd);
    float sp = pt_b[t], sh = ht_b[t];
    #pragma unroll
    for (int kk = 0; kk < 16; ++kk) {
      const float4 wp = ptw4[kk], wh = htw4[kk];
      const float4 av = a4[kk],  hv = hd4[kk];
      sp += av.x*wp.x + av.y*wp.y + av.z*wp.z + av.w*wp.w;
      sh += hv.x*wh.x + hv.y*wh.y + hv.z*wh.z + hv.w*wh.w;
    }
    pf[t] = sp; hf[t] = sh;
  }
  __syncthreads();
  if (t < 64) gate[t] = hf[t] * pf[t];
  __syncthreads();

  // gate linears: wave 0 -> head_gate (hg_w), wave 1 -> pred_gate (pg_w)
  float glin;
  {
    const float* gw = (t < 64) ? hg_w : pg_w;
    float s = (t < 64) ? hg_b[ln] : pg_b[ln];
    const float4* gw4 = reinterpret_cast<const float4*>(gw) + ln * 16;
    const float4* g4  = reinterpret_cast<const float4*>(gate);
    #pragma unroll
    for (int kk = 0; kk < 16; ++kk) {
      const float4 w = gw4[kk], gv = g4[kk];
      s += gv.x*w.x + gv.y*w.y + gv.z*w.z + gv.w*w.w;
    }
    glin = s;
  }
  { // LN + sigmoid per wave
    const float m = wsum64(glin) * (1.f/64.f);
    const float d = glin - m;
    const float var = wsum64(d*d) * (1.f/64.f);
    const float* g  = (t < 64) ? hni_g : pni_g;
    const float* bb = (t < 64) ? hni_b : pni_b;
    const float y = d / sqrtf(var + 1e-5f) * g[ln] + bb[ln];
    const float sg = 1.f / (1.f + expf(-y));
    if (t < 64) hgate[ln] = sg; else pgate[ln] = sg;
  }
  { // LN of the out-halves: wave 0 -> head_feat_out, wave 1 -> pred_feat_out
    const float x = (t < 64) ? hf[64 + ln] : pf[64 + ln];
    const float m = wsum64(x) * (1.f/64.f);
    const float d = x - m;
    const float var = wsum64(d*d) * (1.f/64.f);
    const float* g  = (t < 64) ? hno_g : pno_g;
    const float* bb = (t < 64) ? hno_b : pno_b;
    const float y = d / sqrtf(var + 1e-5f) * g[ln] + bb[ln];
    if (t < 64) hfo[ln] = y; else pfo[ln] = y;
  }
  __syncthreads();
  if (t < 64) upd[t] = pgate[t] * pfo[t] + hgate[t] * hfo[t];
  __syncthreads();
  if (t < 64) {
    const float4* fw4 = reinterpret_cast<const float4*>(fc_w) + t * 16;
    const float4* u4  = reinterpret_cast<const float4*>(upd);
    float s = fc_b[t];
    #pragma unroll
    for (int kk = 0; kk < 16; ++kk) {
      const float4 w = fw4[kk], uv = u4[kk];
      s += uv.x*w.x + uv.y*w.y + uv.z*w.z + uv.w*w.w;
    }
    const float m = wsum64(s) * (1.f/64.f);
    const float d = s - m;
    const float var = wsum64(d*d) * (1.f/64.f);
    const float y = d / sqrtf(var + 1e-5f) * fcn_g[t] + fcn_b[t];
    out[b * 64 + t] = fmaxf(y, 0.f);
  }
}

// ---------------------------------------------------------------------------
extern "C" void kernel_launch(void* const* d_in, const int* in_sizes, int n_in,
                              void* d_out, int out_size, void* d_ws, size_t ws_size,
                              hipStream_t stream) {
  (void)in_sizes; (void)n_in; (void)out_size; (void)ws_size;
  const float* feat     = (const float*)d_in[0];
  const float* head     = (const float*)d_in[1];
  const float* pred     = (const float*)d_in[2];
  const float* dw_w     = (const float*)d_in[3];
  const float* dw_b     = (const float*)d_in[4];
  const float* inc_hw_w = (const float*)d_in[5];
  const float* inc_hw_b = (const float*)d_in[6];
  const float* inc_w_w  = (const float*)d_in[7];
  const float* inc_w_b  = (const float*)d_in[8];
  const float* inc_h_w  = (const float*)d_in[9];
  const float* inc_h_b  = (const float*)d_in[10];
  const float* pt_w  = (const float*)d_in[11];
  const float* pt_b  = (const float*)d_in[12];
  const float* ht_w  = (const float*)d_in[13];
  const float* ht_b  = (const float*)d_in[14];
  const float* pg_w  = (const float*)d_in[15];
  const float* pg_b  = (const float*)d_in[16];
  const float* hg_w  = (const float*)d_in[17];
  const float* hg_b  = (const float*)d_in[18];
  const float* fc_w  = (const float*)d_in[19];
  const float* fc_b  = (const float*)d_in[20];
  const float* pni_g = (const float*)d_in[21];
  const float* pni_b = (const float*)d_in[22];
  const float* hni_g = (const float*)d_in[23];
  const float* hni_b = (const float*)d_in[24];
  const float* pno_g = (const float*)d_in[25];
  const float* pno_b = (const float*)d_in[26];
  const float* hno_g = (const float*)d_in[27];
  const float* hno_b = (const float*)d_in[28];
  const float* fcn_g = (const float*)d_in[29];
  const float* fcn_b = (const float*)d_in[30];

  float* out      = (float*)d_out;
  float* sumF     = (float*)d_ws;          // 1024 floats
  float* predpart = sumF + 1024;           // 1024 floats

  k_fused<<<1152, 256, 0, stream>>>(feat, pred, sumF, predpart);
  k_border<<<384, 256, 0, stream>>>(feat, inc_hw_w, inc_hw_b,
                                    inc_w_w, inc_w_b, inc_h_w, inc_h_b, sumF);
  k_tail<<<16, 128, 0, stream>>>(sumF, predpart, head, dw_w, dw_b,
                                 pt_w, pt_b, ht_w, ht_b,
                                 pg_w, pg_b, hg_w, hg_b, fc_w, fc_b,
                                 pni_g, pni_b, hni_g, hni_b,
                                 pno_g, pno_b, hno_g, hno_b,
                                 fcn_g, fcn_b, out);
}

// Round 4
// 53.657 us; speedup vs baseline: 3.4005x; 1.2111x over previous
//
#include <hip/hip_runtime.h>
#include <math.h>

// ws layout: sumF[1024] floats, then predpart[16*8*8] floats.
//
// Identities (verified exact, absmax 0.0 in rounds 1-2):
//  - sum(irfft2(rfft2(p)*rfft2(f))) over space = sum(p)*sum(f)   (circular conv)
//  - spatial sum of zero-padded depthwise conv = sum_w w[u,v]*RectSum + N*bias,
//    where RectSum needs only the plane total + <=5-wide border row/col sums.
// Border sums are computed INSIDE the single feat sweep:
//  - column id of a thread's float4 is (tid&63), iteration-invariant -> the
//    component accumulators ax..aw ARE column partial sums for special lanes.
//  - border rows live at it in {0,1,62,63} (row = it*4 + wave_id).

typedef float nfloat4 __attribute__((ext_vector_type(4)));

// ---------------------------------------------------------------------------
// Kernel A: blocks 0..127 = pred partial reduction (16 batches x 8 row groups)
//           blocks 128..1151 = feat plane sums (+inline border corrections)
// ---------------------------------------------------------------------------
__global__ __launch_bounds__(256) void k_main(
    const float* __restrict__ feat,
    const float* __restrict__ pred,
    const float* __restrict__ w_hw, const float* __restrict__ b_hw,
    const float* __restrict__ w_w,  const float* __restrict__ b_w,
    const float* __restrict__ w_h,  const float* __restrict__ b_h,
    float* __restrict__ sumF,        // [1024]
    float* __restrict__ predpart)    // [16][8][8]
{
  const int tid  = threadIdx.x;
  const int lane = tid & 63;
  const int wid  = tid >> 6;

  if (blockIdx.x >= 128) {
    const int plane = blockIdx.x - 128;
    const int c = plane & 63;
    const nfloat4* x4 = reinterpret_cast<const nfloat4*>(feat) + (size_t)plane * 16384;

    if (c < 40) {
      // ---- identity plane: pure branch-free sum
      __shared__ float red[4];
      float ax = 0.f, ay = 0.f, az = 0.f, aw = 0.f;
      #pragma unroll 8
      for (int it = 0; it < 64; ++it) {
        const nfloat4 v = __builtin_nontemporal_load(&x4[it * 256 + tid]);
        ax += v.x; ay += v.y; az += v.z; aw += v.w;
      }
      float tot = (ax + ay) + (az + aw);
      #pragma unroll
      for (int off = 32; off; off >>= 1) tot += __shfl_down(tot, off, 64);
      if (lane == 0) red[wid] = tot;
      __syncthreads();
      if (tid == 0) sumF[plane] = (red[0] + red[1]) + (red[2] + red[3]);
      return;
    }

    // ---- conv plane: sum + inline border captures
    __shared__ float s_red[4];
    __shared__ float s_rs[10];        // rows 0..4 -> 0..4, rows 251..255 -> 5..9
    __shared__ float s_cs4[4][10];    // per-wave col partials, same index map
    __shared__ float s_k[4];          // corners (0,0),(0,255),(255,0),(255,255)

    float ax = 0.f, ay = 0.f, az = 0.f, aw = 0.f;
    float rowA = 0.f, rowB = 0.f, rowC = 0.f, rowD = 0.f;
    float v0x = 0.f, v0w = 0.f, v63x = 0.f, v63w = 0.f;
    #pragma unroll 8
    for (int it = 0; it < 64; ++it) {
      const nfloat4 v = __builtin_nontemporal_load(&x4[it * 256 + tid]);
      ax += v.x; ay += v.y; az += v.z; aw += v.w;
      const float s4 = (v.x + v.y) + (v.z + v.w);
      rowA += (it == 0)  ? s4 : 0.f;     // row = wid
      rowB += (it == 1)  ? s4 : 0.f;     // row = 4 + wid
      rowC += (it == 62) ? s4 : 0.f;     // row = 248 + wid
      rowD += (it == 63) ? s4 : 0.f;     // row = 252 + wid
      if (it == 0)  { v0x = v.x;  v0w = v.w; }
      if (it == 63) { v63x = v.x; v63w = v.w; }
    }
    float tot = (ax + ay) + (az + aw);
    float r0 = rowA, r1 = rowB, r2 = rowC, r3 = rowD;
    #pragma unroll
    for (int off = 32; off; off >>= 1) {
      tot += __shfl_down(tot, off, 64);
      r0  += __shfl_down(r0, off, 64);
      r1  += __shfl_down(r1, off, 64);
      r2  += __shfl_down(r2, off, 64);
      r3  += __shfl_down(r3, off, 64);
    }
    if (lane == 0) {
      s_red[wid] = tot;
      s_rs[wid] = r0;                     // rows 0..3
      if (wid == 0) s_rs[4] = r1;         // row 4
      if (wid == 3) s_rs[5] = r2;         // row 251
      s_rs[6 + wid] = r3;                 // rows 252..255
      s_cs4[wid][0] = ax; s_cs4[wid][1] = ay; s_cs4[wid][2] = az; s_cs4[wid][3] = aw;
    }
    if (lane == 1)  { s_cs4[wid][4] = ax; }                // col 4
    if (lane == 62) { s_cs4[wid][5] = aw; }                // col 251
    if (lane == 63) { s_cs4[wid][6] = ax; s_cs4[wid][7] = ay;
                      s_cs4[wid][8] = az; s_cs4[wid][9] = aw; }  // cols 252..255
    if (tid == 0)   s_k[0] = v0x;      // row 0,   col 0
    if (tid == 63)  s_k[1] = v0w;      // row 0,   col 255
    if (tid == 192) s_k[2] = v63x;     // row 255, col 0
    if (tid == 255) s_k[3] = v63w;     // row 255, col 255
    __syncthreads();

    if (tid == 0) {
      const float T = (s_red[0] + s_red[1]) + (s_red[2] + s_red[3]);
      float cs[10];
      #pragma unroll
      for (int k = 0; k < 10; ++k)
        cs[k] = (s_cs4[0][k] + s_cs4[1][k]) + (s_cs4[2][k] + s_cs4[3][k]);
      const float k00 = s_k[0], k01 = s_k[1], k10 = s_k[2], k11 = s_k[3];

      float topP[6], botP[6], leftP[6], rightP[6];
      topP[0] = botP[0] = leftP[0] = rightP[0] = 0.f;
      #pragma unroll
      for (int k = 0; k < 5; ++k) {
        topP[k+1]   = topP[k]   + s_rs[k];
        botP[k+1]   = botP[k]   + s_rs[9-k];
        leftP[k+1]  = leftP[k]  + cs[k];
        rightP[k+1] = rightP[k] + cs[9-k];
      }
      auto rect = [&](int du, int dv) -> float {
        float r = T;
        if (du > 0) r -= topP[du]; else if (du < 0) r -= botP[-du];
        if (dv > 0) r -= leftP[dv]; else if (dv < 0) r -= rightP[-dv];
        if (du > 0 && dv > 0) r += k00;
        else if (du > 0 && dv < 0) r += k01;
        else if (du < 0 && dv > 0) r += k10;
        else if (du < 0 && dv < 0) r += k11;
        return r;
      };
      float S;
      if (c < 48) {                       // 3x3 depthwise, pad (1,1)
        const int g = c - 40; const float* w = w_hw + g * 9;
        S = 65536.f * b_hw[g];
        #pragma unroll
        for (int u = 0; u < 3; ++u)
          #pragma unroll
          for (int v = 0; v < 3; ++v)
            S += w[u*3+v] * rect(u-1, v-1);
      } else if (c < 56) {                // 1x11 depthwise, pad (0,5)
        const int g = c - 48; const float* w = w_w + g * 11;
        S = 65536.f * b_w[g];
        #pragma unroll
        for (int v = 0; v < 11; ++v) S += w[v] * rect(0, v-5);
      } else {                            // 11x1 depthwise, pad (5,0)
        const int g = c - 56; const float* w = w_h + g * 11;
        S = 65536.f * b_h[g];
        #pragma unroll
        for (int u = 0; u < 11; ++u) S += w[u] * rect(u-5, 0);
      }
      sumF[plane] = S;
    }
    return;
  }

  // ---- pred partial: block pb handles output rows [g*32, g*32+32)
  __shared__ float red[12];
  const int pb = blockIdx.x;
  const int b  = pb >> 3;
  const int g  = pb & 7;
  const int j  = tid;                 // output column 0..255
  const float* src = pred + (size_t)b * 16384;

  // jax bilinear 2x (half-pixel, edge clamp): even .25/.75, odd .75/.25
  const int kj = j >> 1;
  int c0, c1; float wc0, wc1;
  if ((j & 1) == 0) { c0 = (kj > 0) ? kj - 1 : 0; c1 = kj; wc0 = 0.25f; wc1 = 0.75f; }
  else              { c0 = kj; c1 = (kj < 127) ? kj + 1 : 127; wc0 = 0.75f; wc1 = 0.25f; }

  float accP = 0.f, accT = 0.f, accC = 0.f, redge = 0.f, cornA = 0.f, cornB = 0.f;
  const int i0 = g * 32;
  #pragma unroll 4
  for (int i = i0; i < i0 + 32; ++i) {
    const int ki = i >> 1;
    int r0, r1; float wr0, wr1;
    if ((i & 1) == 0) { r0 = (ki > 0) ? ki - 1 : 0; r1 = ki; wr0 = 0.25f; wr1 = 0.75f; }
    else              { r0 = ki; r1 = (ki < 127) ? ki + 1 : 127; wr0 = 0.75f; wr1 = 0.25f; }
    const float v = wr0 * (wc0 * src[r0*128 + c0] + wc1 * src[r0*128 + c1])
                  + wr1 * (wc0 * src[r1*128 + c0] + wc1 * src[r1*128 + c1]);
    const float p  = 1.f / (1.f + expf(-v));
    const float pm = 1.f - 1.f / (1.f + expf(-p));
    const float pa = p * pm + p;
    accP += p; accT += pa;
    if (j == 0 || j == 255) accC += pa;
    if (i == 0 || i == 255) {         // only reachable in g==0 / g==7
      redge += pa;
      if (j == 0)   cornA = pa;
      if (j == 255) cornB = pa;
    }
  }
  float a0 = accP, a1 = accT, a2 = redge;
  #pragma unroll
  for (int off = 32; off; off >>= 1) {
    a0 += __shfl_down(a0, off, 64);
    a1 += __shfl_down(a1, off, 64);
    a2 += __shfl_down(a2, off, 64);
  }
  if (lane == 0) { red[wid] = a0; red[4 + wid] = a1; red[8 + wid] = a2; }
  __syncthreads();
  float* pp = predpart + pb * 8;
  if (tid == 0) {
    pp[0] = (red[0] + red[1]) + (red[2] + red[3]);
    pp[1] = (red[4] + red[5]) + (red[6] + red[7]);
    pp[4] = (red[8] + red[9]) + (red[10] + red[11]);
    pp[2] = accC; pp[5] = cornA;
  }
  if (tid == 255) { pp[3] = accC; pp[6] = cornB; }
}

// ---------------------------------------------------------------------------
// Kernel B: combine pred partials -> sumP, then the MLP/LN/gate tail.
// One block per batch, 128 threads (2 waves).
// ---------------------------------------------------------------------------
__device__ __forceinline__ float wsum64(float v) {
  #pragma unroll
  for (int off = 32; off; off >>= 1) v += __shfl_xor(v, off, 64);
  return v;
}

__global__ __launch_bounds__(128) void k_tail(
    const float* __restrict__ sumF, const float* __restrict__ predpart,
    const float* __restrict__ head,
    const float* __restrict__ dw_w, const float* __restrict__ dw_b,
    const float* __restrict__ pt_w, const float* __restrict__ pt_b,
    const float* __restrict__ ht_w, const float* __restrict__ ht_b,
    const float* __restrict__ pg_w, const float* __restrict__ pg_b,
    const float* __restrict__ hg_w, const float* __restrict__ hg_b,
    const float* __restrict__ fc_w, const float* __restrict__ fc_b,
    const float* __restrict__ pni_g, const float* __restrict__ pni_b,
    const float* __restrict__ hni_g, const float* __restrict__ hni_b,
    const float* __restrict__ pno_g, const float* __restrict__ pno_b,
    const float* __restrict__ hno_g, const float* __restrict__ hno_b,
    const float* __restrict__ fcn_g, const float* __restrict__ fcn_b,
    float* __restrict__ out)
{
  const int b = blockIdx.x;
  const int t = threadIdx.x;      // 0..127
  const int ln = t & 63;
  __shared__ float a[64], hd[64], pf[128], hf[128], gate[64];
  __shared__ float hgate[64], pgate[64], pfo[64], hfo[64], upd[64];
  __shared__ float s_sP;

  const float sf = (t < 64) ? sumF[b * 64 + t] : 0.f;
  if (t < 64) hd[t] = head[b * 64 + t];

  if (t == 0) {
    const float* pp = predpart + b * 64;   // [8][8], fixed combine order
    float P = 0.f, T = 0.f, C0 = 0.f, C255 = 0.f;
    #pragma unroll
    for (int g = 0; g < 8; ++g) {
      P += pp[g*8 + 0]; T += pp[g*8 + 1]; C0 += pp[g*8 + 2]; C255 += pp[g*8 + 3];
    }
    const float R0 = pp[0*8 + 4], R255 = pp[7*8 + 4];
    const float k00 = pp[0*8 + 5], k01 = pp[0*8 + 6];
    const float k10 = pp[7*8 + 5], k11 = pp[7*8 + 6];
    auto rect = [&](int du, int dv) -> float {
      float r = T;
      if (du > 0) r -= R0; else if (du < 0) r -= R255;
      if (dv > 0) r -= C0; else if (dv < 0) r -= C255;
      if (du > 0 && dv > 0) r += k00;
      else if (du > 0 && dv < 0) r += k01;
      else if (du < 0 && dv > 0) r += k10;
      else if (du < 0 && dv < 0) r += k11;
      return r;
    };
    float S = P + 65536.f * dw_b[0];
    #pragma unroll
    for (int u = 0; u < 3; ++u)
      #pragma unroll
      for (int v = 0; v < 3; ++v)
        S += dw_w[u*3+v] * rect(u-1, v-1);
    s_sP = S;
  }
  __syncthreads();
  if (t < 64) a[t] = sf * s_sP;
  __syncthreads();

  { // pred_feat / head_feat linears (128 outputs each), float4 weight rows
    const float4* ptw4 = reinterpret_cast<const float4*>(pt_w) + t * 16;
    const float4* htw4 = reinterpret_cast<const float4*>(ht_w) + t * 16;
    const float4* a4  = reinterpret_cast<const float4*>(a);
    const float4* hd4 = reinterpret_cast<const float4*>(hd);
    float sp = pt_b[t], sh = ht_b[t];
    #pragma unroll
    for (int kk = 0; kk < 16; ++kk) {
      const float4 wp = ptw4[kk], wh = htw4[kk];
      const float4 av = a4[kk],  hv = hd4[kk];
      sp += av.x*wp.x + av.y*wp.y + av.z*wp.z + av.w*wp.w;
      sh += hv.x*wh.x + hv.y*wh.y + hv.z*wh.z + hv.w*wh.w;
    }
    pf[t] = sp; hf[t] = sh;
  }
  __syncthreads();
  if (t < 64) gate[t] = hf[t] * pf[t];
  __syncthreads();

  float glin;
  {
    const float* gw = (t < 64) ? hg_w : pg_w;
    float s = (t < 64) ? hg_b[ln] : pg_b[ln];
    const float4* gw4 = reinterpret_cast<const float4*>(gw) + ln * 16;
    const float4* g4  = reinterpret_cast<const float4*>(gate);
    #pragma unroll
    for (int kk = 0; kk < 16; ++kk) {
      const float4 w = gw4[kk], gv = g4[kk];
      s += gv.x*w.x + gv.y*w.y + gv.z*w.z + gv.w*w.w;
    }
    glin = s;
  }
  { // LN + sigmoid per wave
    const float m = wsum64(glin) * (1.f/64.f);
    const float d = glin - m;
    const float var = wsum64(d*d) * (1.f/64.f);
    const float* g  = (t < 64) ? hni_g : pni_g;
    const float* bb = (t < 64) ? hni_b : pni_b;
    const float y = d / sqrtf(var + 1e-5f) * g[ln] + bb[ln];
    const float sg = 1.f / (1.f + expf(-y));
    if (t < 64) hgate[ln] = sg; else pgate[ln] = sg;
  }
  { // LN of the out-halves
    const float x = (t < 64) ? hf[64 + ln] : pf[64 + ln];
    const float m = wsum64(x) * (1.f/64.f);
    const float d = x - m;
    const float var = wsum64(d*d) * (1.f/64.f);
    const float* g  = (t < 64) ? hno_g : pno_g;
    const float* bb = (t < 64) ? hno_b : pno_b;
    const float y = d / sqrtf(var + 1e-5f) * g[ln] + bb[ln];
    if (t < 64) hfo[ln] = y; else pfo[ln] = y;
  }
  __syncthreads();
  if (t < 64) upd[t] = pgate[t] * pfo[t] + hgate[t] * hfo[t];
  __syncthreads();
  if (t < 64) {
    const float4* fw4 = reinterpret_cast<const float4*>(fc_w) + t * 16;
    const float4* u4  = reinterpret_cast<const float4*>(upd);
    float s = fc_b[t];
    #pragma unroll
    for (int kk = 0; kk < 16; ++kk) {
      const float4 w = fw4[kk], uv = u4[kk];
      s += uv.x*w.x + uv.y*w.y + uv.z*w.z + uv.w*w.w;
    }
    const float m = wsum64(s) * (1.f/64.f);
    const float d = s - m;
    const float var = wsum64(d*d) * (1.f/64.f);
    const float y = d / sqrtf(var + 1e-5f) * fcn_g[t] + fcn_b[t];
    out[b * 64 + t] = fmaxf(y, 0.f);
  }
}

// ---------------------------------------------------------------------------
extern "C" void kernel_launch(void* const* d_in, const int* in_sizes, int n_in,
                              void* d_out, int out_size, void* d_ws, size_t ws_size,
                              hipStream_t stream) {
  (void)in_sizes; (void)n_in; (void)out_size; (void)ws_size;
  const float* feat     = (const float*)d_in[0];
  const float* head     = (const float*)d_in[1];
  const float* pred     = (const float*)d_in[2];
  const float* dw_w     = (const float*)d_in[3];
  const float* dw_b     = (const float*)d_in[4];
  const float* inc_hw_w = (const float*)d_in[5];
  const float* inc_hw_b = (const float*)d_in[6];
  const float* inc_w_w  = (const float*)d_in[7];
  const float* inc_w_b  = (const float*)d_in[8];
  const float* inc_h_w  = (const float*)d_in[9];
  const float* inc_h_b  = (const float*)d_in[10];
  const float* pt_w  = (const float*)d_in[11];
  const float* pt_b  = (const float*)d_in[12];
  const float* ht_w  = (const float*)d_in[13];
  const float* ht_b  = (const float*)d_in[14];
  const float* pg_w  = (const float*)d_in[15];
  const float* pg_b  = (const float*)d_in[16];
  const float* hg_w  = (const float*)d_in[17];
  const float* hg_b  = (const float*)d_in[18];
  const float* fc_w  = (const float*)d_in[19];
  const float* fc_b  = (const float*)d_in[20];
  const float* pni_g = (const float*)d_in[21];
  const float* pni_b = (const float*)d_in[22];
  const float* hni_g = (const float*)d_in[23];
  const float* hni_b = (const float*)d_in[24];
  const float* pno_g = (const float*)d_in[25];
  const float* pno_b = (const float*)d_in[26];
  const float* hno_g = (const float*)d_in[27];
  const float* hno_b = (const float*)d_in[28];
  const float* fcn_g = (const float*)d_in[29];
  const float* fcn_b = (const float*)d_in[30];

  float* out      = (float*)d_out;
  float* sumF     = (float*)d_ws;          // 1024 floats
  float* predpart = sumF + 1024;           // 1024 floats

  k_main<<<1152, 256, 0, stream>>>(feat, pred,
                                   inc_hw_w, inc_hw_b, inc_w_w, inc_w_b,
                                   inc_h_w, inc_h_b, sumF, predpart);
  k_tail<<<16, 128, 0, stream>>>(sumF, predpart, head, dw_w, dw_b,
                                 pt_w, pt_b, ht_w, ht_b,
                                 pg_w, pg_b, hg_w, hg_b, fc_w, fc_b,
                                 pni_g, pni_b, hni_g, hni_b,
                                 pno_g, pno_b, hno_g, hno_b,
                                 fcn_g, fcn_b, out);
}